// Round 1
// 165.267 us; speedup vs baseline: 1.0437x; 1.0437x over previous
//
#include <hip/hip_runtime.h>

// CRF loss, B=1024, T=512, K=32 — chunked associative scan, register-resident.
//
// Phase 1 (crf_chunk): per chunk (8192 waves): N <- D_t (E^T N), in registers:
//   * contraction index k is PERMUTED (pi: slot q*8+j <-> orig row q*4+j /
//     16+q*4+j-4). A (= E^T, constant) is packed in pi-order; under pi the
//     next step's B-fragment IS the current lane's own C fragments ->
//     NO LDS and NO cross-lane ops in the serial loop.
//   * step = 4x mfma_16x16x32_bf16 + 8 exp + vector scale muls + 8 v_perm packs
//   * mask folded to a 64-bit ballot (SALU test); chunk-0's t=0 handled by
//     clearing ballot bit 0 -> uniform 64-step loops, unroll-2 ping-pong
//   * renorm every 8 applied steps by element (0,0) via readfirstlane
//   * one LDS transpose at kernel end for the M^T dump (negligible)
//   * 256-thread blocks (4 independent waves, one chunk each): the old
//     64-thread blocks hit the 16-WG/CU cap -> 52% occupancy. 4 waves/WG
//     gives 32 waves/CU at 36 VGPRs.
// Phase 2 (crf_combine): one wave per sequence, all 8 chunk matrices loaded
//   to registers up-front (16x dwordx4 in flight), lane-pair split matvecs,
//   no LDS. Memory-bound at full pipelining instead of latency-bound.

#define K32 32
#define Tt  512
#define NCH 8
#define CHL 64

typedef float  float4v __attribute__((ext_vector_type(4)));
typedef short  short8v __attribute__((ext_vector_type(8)));

__device__ inline float bf2f_lo(unsigned d) { return __uint_as_float(d << 16); }
__device__ inline float bf2f_hi(unsigned d) { return __uint_as_float(d & 0xFFFF0000u); }

// pack two f32 -> bf16x2 dword by truncation: low16 = hi16(lo), high16 = hi16(hi)
__device__ inline unsigned pack_trunc(float hi, float lo) {
    return __builtin_amdgcn_perm(__float_as_uint(hi), __float_as_uint(lo), 0x07060302u);
}
// round-to-nearest-even bf16 (one-time constants only)
__device__ inline unsigned short f2bf_rne(float x) {
    unsigned u = __float_as_uint(x);
    return (unsigned short)((u + 0x7FFFu + ((u >> 16) & 1u)) >> 16);
}

union F8 { unsigned u[4]; short8v v; };

// ---------------- Phase 1: per-chunk matrix product (register-resident) ----------------
__global__ __launch_bounds__(256, 8) void crf_chunk(
    const int*   __restrict__ labels,
    const float* __restrict__ y_pred,
    const float* __restrict__ trans,
    const float* __restrict__ mask,
    unsigned*    __restrict__ wsMT,   // [8192][512] dwords: M^T row-major bf16x2
    float*       __restrict__ wsS,    // [8192] log-scale per chunk
    float*       __restrict__ wsSc)   // [8192] path-score per chunk
{
    __shared__ unsigned short NcmAll[4][32 * 40];   // per-wave transpose scratch

    const int lane = threadIdx.x & 63;
    const int wv   = threadIdx.x >> 6;
    const int gw   = blockIdx.x * 4 + wv;     // global wave id == old blockIdx
    const int n    = lane & 15;
    const int q    = lane >> 4;
    const int seq  = gw >> 3;
    const int c    = gw & 7;

    unsigned short* Ncm = NcmAll[wv];

    const float* yp  = y_pred + (size_t)seq * Tt * K32;
    const int*   lb  = labels + (size_t)seq * Tt;
    const float* mkp = mask   + (size_t)seq * Tt;

    // ---- chunk path score (parallel: 64 lanes <-> 64 timesteps) ----
    float sc;
    float mlane;
    {
        const int t = c * CHL + lane;
        const int   lab0 = lb[t];
        mlane = mkp[t];
        sc = yp[t * K32 + lab0] * mlane;
        if (t < Tt - 1) {
            sc += trans[lab0 * K32 + lb[t + 1]] * (mlane * mkp[t + 1]);
        }
#pragma unroll
        for (int s = 1; s < 64; s <<= 1) sc += __shfl_xor(sc, s, 64);
    }

    // ---- mask ballot; chunk 0 skips t=0 via cleared bit ----
    unsigned long long mbits = __ballot(mlane != 0.0f);
    if (c == 0) mbits &= ~1ull;

    // ---- constant A in pi-k-order: slot q*8+j <-> orig k = q*4+j | 16+q*4+(j-4) ----
    F8 AE0, AE1;
#pragma unroll
    for (int h = 0; h < 4; ++h) {
        const int k0 = (h < 2) ? (q * 4 + 2 * h) : (16 + q * 4 + 2 * (h - 2));
        const int k1 = k0 + 1;
        AE0.u[h] = ((unsigned)f2bf_rne(__expf(trans[k0 * K32 + n]) * 0.03125f)) |
                   (((unsigned)f2bf_rne(__expf(trans[k1 * K32 + n]) * 0.03125f)) << 16);
        AE1.u[h] = ((unsigned)f2bf_rne(__expf(trans[k0 * K32 + 16 + n]) * 0.03125f)) |
                   (((unsigned)f2bf_rne(__expf(trans[k1 * K32 + 16 + n]) * 0.03125f)) << 16);
    }

    // ---- B = identity fragments (pi-order) ----
    F8 B0, B1;
#pragma unroll
    for (int h = 0; h < 4; ++h) {
        const int r0 = (h < 2) ? (q * 4 + 2 * h) : (16 + q * 4 + 2 * (h - 2));
        const int r1 = r0 + 1;
        unsigned w0 = 0, w1 = 0;
        if (r0 == n)      w0 |= 0x3F80u;
        if (r1 == n)      w0 |= 0x3F800000u;
        if (r0 == 16 + n) w1 |= 0x3F80u;
        if (r1 == 16 + n) w1 |= 0x3F800000u;
        B0.u[h] = w0;
        B1.u[h] = w1;
    }

    float Slog    = 0.0f;
    int   applied = 0;

    // emit row-scale: rows q*4..+3 and 16+q*4..+3 (contiguous float4 each)
    const float4* ypr0 = (const float4*)(yp + q * 4);        // index: t*8
    const float4* ypr1 = (const float4*)(yp + 16 + q * 4);

    const int tbase = c * CHL;
    const int tmax  = tbase + CHL - 1;

    float4 eA0 = ypr0[(size_t)tbase * 8],       eA1 = ypr1[(size_t)tbase * 8];
    float4 eB0 = ypr0[(size_t)(tbase + 1) * 8], eB1 = ypr1[(size_t)(tbase + 1) * 8];

    auto dostep = [&](int t, const float4& e0, const float4& e1) {
        if ((mbits >> (t & 63)) & 1ull) {         // wave-uniform SALU test
            float4v c00 = {0.f, 0.f, 0.f, 0.f}, c01 = {0.f, 0.f, 0.f, 0.f};
            float4v c10 = {0.f, 0.f, 0.f, 0.f}, c11 = {0.f, 0.f, 0.f, 0.f};
            c00 = __builtin_amdgcn_mfma_f32_16x16x32_bf16(AE0.v, B0.v, c00, 0, 0, 0);
            c01 = __builtin_amdgcn_mfma_f32_16x16x32_bf16(AE0.v, B1.v, c01, 0, 0, 0);
            c10 = __builtin_amdgcn_mfma_f32_16x16x32_bf16(AE1.v, B0.v, c10, 0, 0, 0);
            c11 = __builtin_amdgcn_mfma_f32_16x16x32_bf16(AE1.v, B1.v, c11, 0, 0, 0);

            // D_t row-scale (vector form -> v_pk_mul_f32 eligible)
            const float4v sv0 = {__expf(e0.x), __expf(e0.y), __expf(e0.z), __expf(e0.w)};
            const float4v sv1 = {__expf(e1.x), __expf(e1.y), __expf(e1.z), __expf(e1.w)};
            c00 *= sv0; c01 *= sv0; c10 *= sv1; c11 *= sv1;

            if ((applied & 7) == 7) {             // element-(0,0) renorm
                const float cn = __uint_as_float(
                    __builtin_amdgcn_readfirstlane(__float_as_uint(c00[0])));
                const float rs = 1.0f / cn;
                c00 *= rs; c01 *= rs; c10 *= rs; c11 *= rs;
                Slog += __logf(cn);
            }
            ++applied;

            // pack C -> next B (pi-order makes this the lane's own data)
            B0.u[0] = pack_trunc(c00[1], c00[0]);
            B0.u[1] = pack_trunc(c00[3], c00[2]);
            B0.u[2] = pack_trunc(c10[1], c10[0]);
            B0.u[3] = pack_trunc(c10[3], c10[2]);
            B1.u[0] = pack_trunc(c01[1], c01[0]);
            B1.u[1] = pack_trunc(c01[3], c01[2]);
            B1.u[2] = pack_trunc(c11[1], c11[0]);
            B1.u[3] = pack_trunc(c11[3], c11[2]);
        }
    };

    for (int i = 0; i < CHL; i += 2) {            // uniform 64 steps, unroll-2
        const int t = tbase + i;
        dostep(t, eA0, eA1);
        {
            const int tn = (t + 2 <= tmax) ? (t + 2) : tmax;
            eA0 = ypr0[(size_t)tn * 8]; eA1 = ypr1[(size_t)tn * 8];
        }
        dostep(t + 1, eB0, eB1);
        {
            const int tn = (t + 3 <= tmax) ? (t + 3) : tmax;
            eB0 = ypr0[(size_t)tn * 8]; eB1 = ypr1[(size_t)tn * 8];
        }
    }

    // ---- one-time LDS transpose: B frags -> col-major, then dump M^T row-major ----
    {
        unsigned* Nd = (unsigned*)Ncm;            // dword view, col stride 20
        *(uint2*)&Nd[n * 20 + q * 2]            = make_uint2(B0.u[0], B0.u[1]);  // col n, rows q*4..
        *(uint2*)&Nd[n * 20 + 8 + q * 2]        = make_uint2(B0.u[2], B0.u[3]);  // col n, rows 16+q*4..
        *(uint2*)&Nd[(16 + n) * 20 + q * 2]     = make_uint2(B1.u[0], B1.u[1]);
        *(uint2*)&Nd[(16 + n) * 20 + 8 + q * 2] = make_uint2(B1.u[2], B1.u[3]);
    }
    unsigned* md = wsMT + (size_t)gw * 512;
    for (int idx = lane; idx < 512; idx += 64) {
        const int k = idx >> 4, d = idx & 15;
        const unsigned lo = Ncm[(2 * d) * 40 + k];
        const unsigned hi = Ncm[(2 * d + 1) * 40 + k];
        md[idx] = lo | (hi << 16);
    }
    if (lane == 0) {
        wsS[gw]  = Slog + (float)applied * 3.46573590f;   // + applied*5*ln2
        wsSc[gw] = sc;
    }
}

// ---------------- Phase 2: serial combine (register-resident, 1 wave/seq) ----------------
// Lane (j, h=lane>>5) accumulates cols 16h..16h+15 of output row j; the two
// halves are summed with one shfl_xor(32). All 16 dwordx4 matrix loads are
// issued before any use -> full memory pipelining (no LDS round-trip).
__global__ __launch_bounds__(64) void crf_combine(
    const float*    __restrict__ y_pred,
    const unsigned* __restrict__ wsMT,
    const float*    __restrict__ wsS,
    const float*    __restrict__ wsSc,
    float*          __restrict__ out)
{
    const int lane = threadIdx.x;
    const int h    = lane >> 5;
    const int j    = lane & 31;
    const int seq  = blockIdx.x;

    // chunk cc, row j, dwords j*16 + 8h .. +8h+7  (cols 16h..16h+15)
    const uint4* mb = (const uint4*)(wsMT + (size_t)seq * NCH * 512);
    uint4 mA[NCH], mB[NCH];
#pragma unroll
    for (int cc = 0; cc < NCH; ++cc) {
        mA[cc] = mb[cc * 128 + j * 4 + 2 * h];
        mB[cc] = mb[cc * 128 + j * 4 + 2 * h + 1];
    }

    const float* yp = y_pred + (size_t)seq * Tt * K32;
    const float a0 = yp[j];                    // mirrored in both halves
    const float m0 = __shfl(a0, 0, 64);
    float p = __expf(a0 - m0);                 // p[j], mirrored
    float S = m0;

    float scs = 0.0f;
#pragma unroll
    for (int cc = 0; cc < NCH; ++cc) {
        S   += wsS[seq * NCH + cc];
        scs += wsSc[seq * NCH + cc];
    }

    const int cb = h << 4;                     // column base for this half
#pragma unroll
    for (int cc = 0; cc < NCH; ++cc) {
        const float cn = __shfl(p, 0, 64);     // old p[0] (deferred renorm)
        const unsigned u0 = mA[cc].x, u1 = mA[cc].y, u2 = mA[cc].z, u3 = mA[cc].w;
        const unsigned u4 = mB[cc].x, u5 = mB[cc].y, u6 = mB[cc].z, u7 = mB[cc].w;
        float acc = 0.0f;
        acc = fmaf(__shfl(p, cb +  0, 64), bf2f_lo(u0), acc);
        acc = fmaf(__shfl(p, cb +  1, 64), bf2f_hi(u0), acc);
        acc = fmaf(__shfl(p, cb +  2, 64), bf2f_lo(u1), acc);
        acc = fmaf(__shfl(p, cb +  3, 64), bf2f_hi(u1), acc);
        acc = fmaf(__shfl(p, cb +  4, 64), bf2f_lo(u2), acc);
        acc = fmaf(__shfl(p, cb +  5, 64), bf2f_hi(u2), acc);
        acc = fmaf(__shfl(p, cb +  6, 64), bf2f_lo(u3), acc);
        acc = fmaf(__shfl(p, cb +  7, 64), bf2f_hi(u3), acc);
        acc = fmaf(__shfl(p, cb +  8, 64), bf2f_lo(u4), acc);
        acc = fmaf(__shfl(p, cb +  9, 64), bf2f_hi(u4), acc);
        acc = fmaf(__shfl(p, cb + 10, 64), bf2f_lo(u5), acc);
        acc = fmaf(__shfl(p, cb + 11, 64), bf2f_hi(u5), acc);
        acc = fmaf(__shfl(p, cb + 12, 64), bf2f_lo(u6), acc);
        acc = fmaf(__shfl(p, cb + 13, 64), bf2f_hi(u6), acc);
        acc = fmaf(__shfl(p, cb + 14, 64), bf2f_lo(u7), acc);
        acc = fmaf(__shfl(p, cb + 15, 64), bf2f_hi(u7), acc);
        acc += __shfl_xor(acc, 32, 64);        // combine halves -> full dot, mirrored
        p = acc * (1.0f / cn);
        S += __logf(cn);
    }

    float sp = p;
    sp += __shfl_xor(sp,  1, 64);
    sp += __shfl_xor(sp,  2, 64);
    sp += __shfl_xor(sp,  4, 64);
    sp += __shfl_xor(sp,  8, 64);
    sp += __shfl_xor(sp, 16, 64);

    if (lane == 0) {
        out[seq] = S + __logf(sp) - scs;
    }
}

extern "C" void kernel_launch(void* const* d_in, const int* in_sizes, int n_in,
                              void* d_out, int out_size, void* d_ws, size_t ws_size,
                              hipStream_t stream) {
    const int*   labels = (const int*)  d_in[0];
    const float* y_pred = (const float*)d_in[1];
    const float* trans  = (const float*)d_in[2];
    const float* mask   = (const float*)d_in[3];
    float* out = (float*)d_out;

    // workspace carve: M^T (16 MB) | S (32 KB) | Sc (32 KB)
    unsigned* wsMT = (unsigned*)d_ws;
    float* wsS  = (float*)((char*)d_ws + (size_t)1024 * NCH * 512 * 4);
    float* wsSc = wsS + 1024 * NCH;

    crf_chunk<<<2048, 256, 0, stream>>>(labels, y_pred, trans, mask, wsMT, wsS, wsSc);
    crf_combine<<<1024, 64, 0, stream>>>(y_pred, wsMT, wsS, wsSc, out);
}

// Round 2
// 153.583 us; speedup vs baseline: 1.1231x; 1.0761x over previous
//
#include <hip/hip_runtime.h>

// CRF loss, B=1024, T=512, K=32 — chunked associative scan, register-resident.
//
// Phase 1 (crf_chunk): per chunk (8192 waves): N <- D_t (E^T N), in registers:
//   * contraction index k is PERMUTED (pi: slot q*8+j <-> orig row q*4+j /
//     16+q*4+j-4). A (= E^T, constant) is packed in pi-order; under pi the
//     next step's B-fragment IS the current lane's own C fragments ->
//     NO LDS and NO cross-lane ops in the serial loop.
//   * D_t row-scales are DEDUPED: one coalesced dword load yp[t*32+(lane&31)]
//     (128B broadcast to both wave halves), ONE __expf per step, then 8
//     ds_bpermute to route row r's scale to the lanes that need it.
//     (Old code: 8 redundant __expf per lane per step = 16x duplicated work,
//      ~140 VALU-cycles/step on the quarter-rate trans pipe.)
//   * wave id scalarized via readfirstlane -> seq/c/tbase and all per-step
//     load addressing is SALU, not 64-bit vector math.
//   * step = 4x mfma_16x16x32_bf16 + 1 exp + 8 bpermute + 8 pk_mul + 8 v_perm
//   * mask folded to a 64-bit ballot (SALU test); chunk-0's t=0 handled by
//     clearing ballot bit 0 -> uniform 64-step loops, 8-step unrolled ring
//   * renorm every 8 applied steps by element (0,0) via readfirstlane
//   * one LDS transpose at kernel end for the M^T dump (negligible)
// Phase 2 (crf_combine): one wave per sequence, all 8 chunk matrices loaded
//   to registers up-front, lane-pair split matvecs, no LDS.

#define K32 32
#define Tt  512
#define NCH 8
#define CHL 64

typedef float  float4v __attribute__((ext_vector_type(4)));
typedef short  short8v __attribute__((ext_vector_type(8)));

__device__ inline float bf2f_lo(unsigned d) { return __uint_as_float(d << 16); }
__device__ inline float bf2f_hi(unsigned d) { return __uint_as_float(d & 0xFFFF0000u); }

// pack two f32 -> bf16x2 dword by truncation: low16 = hi16(lo), high16 = hi16(hi)
__device__ inline unsigned pack_trunc(float hi, float lo) {
    return __builtin_amdgcn_perm(__float_as_uint(hi), __float_as_uint(lo), 0x07060302u);
}
// round-to-nearest-even bf16 (one-time constants only)
__device__ inline unsigned short f2bf_rne(float x) {
    unsigned u = __float_as_uint(x);
    return (unsigned short)((u + 0x7FFFu + ((u >> 16) & 1u)) >> 16);
}

__device__ inline float bperm(int idx, float v) {
    return __int_as_float(__builtin_amdgcn_ds_bpermute(idx, __float_as_int(v)));
}

union F8 { unsigned u[4]; short8v v; };

// ---------------- Phase 1: per-chunk matrix product (register-resident) ----------------
__global__ __launch_bounds__(256, 8) void crf_chunk(
    const int*   __restrict__ labels,
    const float* __restrict__ y_pred,
    const float* __restrict__ trans,
    const float* __restrict__ mask,
    unsigned*    __restrict__ wsMT,   // [8192][512] dwords: M^T row-major bf16x2
    float*       __restrict__ wsS,    // [8192] log-scale per chunk
    float*       __restrict__ wsSc)   // [8192] path-score per chunk
{
    __shared__ unsigned short NcmAll[4][32 * 40];   // per-wave transpose scratch

    const int lane = threadIdx.x & 63;
    const int wv   = __builtin_amdgcn_readfirstlane(threadIdx.x >> 6);  // wave-uniform -> SGPR
    const int gw   = blockIdx.x * 4 + wv;     // global wave id (scalar)
    const int n    = lane & 15;
    const int q    = lane >> 4;
    const int seq  = gw >> 3;                 // scalar
    const int c    = gw & 7;                  // scalar

    unsigned short* Ncm = NcmAll[wv];

    const float* yp  = y_pred + (size_t)seq * Tt * K32;
    const int*   lb  = labels + (size_t)seq * Tt;
    const float* mkp = mask   + (size_t)seq * Tt;

    // ---- chunk path score (parallel: 64 lanes <-> 64 timesteps) ----
    float sc;
    float mlane;
    {
        const int t = c * CHL + lane;
        const int   lab0 = lb[t];
        mlane = mkp[t];
        sc = yp[t * K32 + lab0] * mlane;
        if (t < Tt - 1) {
            sc += trans[lab0 * K32 + lb[t + 1]] * (mlane * mkp[t + 1]);
        }
#pragma unroll
        for (int s = 1; s < 64; s <<= 1) sc += __shfl_xor(sc, s, 64);
    }

    // ---- mask ballot; chunk 0 skips t=0 via cleared bit ----
    unsigned long long mbits = __ballot(mlane != 0.0f);
    if (c == 0) mbits &= ~1ull;

    // ---- constant A in pi-k-order: slot q*8+j <-> orig k = q*4+j | 16+q*4+(j-4) ----
    F8 AE0, AE1;
#pragma unroll
    for (int h = 0; h < 4; ++h) {
        const int k0 = (h < 2) ? (q * 4 + 2 * h) : (16 + q * 4 + 2 * (h - 2));
        const int k1 = k0 + 1;
        AE0.u[h] = ((unsigned)f2bf_rne(__expf(trans[k0 * K32 + n]) * 0.03125f)) |
                   (((unsigned)f2bf_rne(__expf(trans[k1 * K32 + n]) * 0.03125f)) << 16);
        AE1.u[h] = ((unsigned)f2bf_rne(__expf(trans[k0 * K32 + 16 + n]) * 0.03125f)) |
                   (((unsigned)f2bf_rne(__expf(trans[k1 * K32 + 16 + n]) * 0.03125f)) << 16);
    }

    // ---- B = identity fragments (pi-order) ----
    F8 B0, B1;
#pragma unroll
    for (int h = 0; h < 4; ++h) {
        const int r0 = (h < 2) ? (q * 4 + 2 * h) : (16 + q * 4 + 2 * (h - 2));
        const int r1 = r0 + 1;
        unsigned w0 = 0, w1 = 0;
        if (r0 == n)      w0 |= 0x3F80u;
        if (r1 == n)      w0 |= 0x3F800000u;
        if (r0 == 16 + n) w1 |= 0x3F80u;
        if (r1 == 16 + n) w1 |= 0x3F800000u;
        B0.u[h] = w0;
        B1.u[h] = w1;
    }

    // ---- bpermute byte-indices for the row-scale gather (constant per lane) ----
    // sv0[j] = scale of row q*4+j  -> lane q*4+j ; sv1[j] -> lane 16+q*4+j
    const int ix0 = (q * 4 + 0) << 2;
    const int ix1 = (q * 4 + 1) << 2;
    const int ix2 = (q * 4 + 2) << 2;
    const int ix3 = (q * 4 + 3) << 2;
    const int jx0 = ix0 + 64, jx1 = ix1 + 64, jx2 = ix2 + 64, jx3 = ix3 + 64;

    float Slog    = 0.0f;
    int   applied = 0;

    const int tbase = c * CHL;                 // scalar
    const int tmax  = tbase + CHL - 1;
    const int ln32  = lane & 31;

    // emit scale source: yp[t*32 + (lane&31)] — 128B coalesced, both halves same
    auto L = [&](int t) -> float { return yp[t * K32 + ln32]; };

    // 8-deep emit ring (prefetch distance 8 steps)
    float ev0 = L(tbase + 0), ev1 = L(tbase + 1), ev2 = L(tbase + 2), ev3 = L(tbase + 3);
    float ev4 = L(tbase + 4), ev5 = L(tbase + 5), ev6 = L(tbase + 6), ev7 = L(tbase + 7);

    auto dostep = [&](int t, float ev) {
        if ((mbits >> (t & 63)) & 1ull) {         // wave-uniform SALU test
            float4v c00 = {0.f, 0.f, 0.f, 0.f}, c01 = {0.f, 0.f, 0.f, 0.f};
            float4v c10 = {0.f, 0.f, 0.f, 0.f}, c11 = {0.f, 0.f, 0.f, 0.f};
            c00 = __builtin_amdgcn_mfma_f32_16x16x32_bf16(AE0.v, B0.v, c00, 0, 0, 0);
            c01 = __builtin_amdgcn_mfma_f32_16x16x32_bf16(AE0.v, B1.v, c01, 0, 0, 0);
            c10 = __builtin_amdgcn_mfma_f32_16x16x32_bf16(AE1.v, B0.v, c10, 0, 0, 0);
            c11 = __builtin_amdgcn_mfma_f32_16x16x32_bf16(AE1.v, B1.v, c11, 0, 0, 0);

            // D_t row-scale: 1 exp + 8 bpermute (replaces 8 redundant exps)
            const float pe = __expf(ev);
            const float4v sv0 = {bperm(ix0, pe), bperm(ix1, pe), bperm(ix2, pe), bperm(ix3, pe)};
            const float4v sv1 = {bperm(jx0, pe), bperm(jx1, pe), bperm(jx2, pe), bperm(jx3, pe)};
            c00 *= sv0; c01 *= sv0; c10 *= sv1; c11 *= sv1;

            if ((applied & 7) == 7) {             // element-(0,0) renorm
                const float cn = __uint_as_float(
                    __builtin_amdgcn_readfirstlane(__float_as_uint(c00[0])));
                const float rs = 1.0f / cn;
                c00 *= rs; c01 *= rs; c10 *= rs; c11 *= rs;
                Slog += __logf(cn);
            }
            ++applied;

            // pack C -> next B (pi-order makes this the lane's own data)
            B0.u[0] = pack_trunc(c00[1], c00[0]);
            B0.u[1] = pack_trunc(c00[3], c00[2]);
            B0.u[2] = pack_trunc(c10[1], c10[0]);
            B0.u[3] = pack_trunc(c10[3], c10[2]);
            B1.u[0] = pack_trunc(c01[1], c01[0]);
            B1.u[1] = pack_trunc(c01[3], c01[2]);
            B1.u[2] = pack_trunc(c11[1], c11[0]);
            B1.u[3] = pack_trunc(c11[3], c11[2]);
        }
    };

    for (int i = 0; i < CHL; i += 8) {            // uniform 64 steps, 8-step ring
        const int t = tbase + i;
        dostep(t + 0, ev0);  ev0 = L(min(t +  8, tmax));
        dostep(t + 1, ev1);  ev1 = L(min(t +  9, tmax));
        dostep(t + 2, ev2);  ev2 = L(min(t + 10, tmax));
        dostep(t + 3, ev3);  ev3 = L(min(t + 11, tmax));
        dostep(t + 4, ev4);  ev4 = L(min(t + 12, tmax));
        dostep(t + 5, ev5);  ev5 = L(min(t + 13, tmax));
        dostep(t + 6, ev6);  ev6 = L(min(t + 14, tmax));
        dostep(t + 7, ev7);  ev7 = L(min(t + 15, tmax));
    }

    // ---- one-time LDS transpose: B frags -> col-major, then dump M^T row-major ----
    {
        unsigned* Nd = (unsigned*)Ncm;            // dword view, col stride 20
        *(uint2*)&Nd[n * 20 + q * 2]            = make_uint2(B0.u[0], B0.u[1]);  // col n, rows q*4..
        *(uint2*)&Nd[n * 20 + 8 + q * 2]        = make_uint2(B0.u[2], B0.u[3]);  // col n, rows 16+q*4..
        *(uint2*)&Nd[(16 + n) * 20 + q * 2]     = make_uint2(B1.u[0], B1.u[1]);
        *(uint2*)&Nd[(16 + n) * 20 + 8 + q * 2] = make_uint2(B1.u[2], B1.u[3]);
    }
    unsigned* md = wsMT + (size_t)gw * 512;
    for (int idx = lane; idx < 512; idx += 64) {
        const int k = idx >> 4, d = idx & 15;
        const unsigned lo = Ncm[(2 * d) * 40 + k];
        const unsigned hi = Ncm[(2 * d + 1) * 40 + k];
        md[idx] = lo | (hi << 16);
    }
    if (lane == 0) {
        wsS[gw]  = Slog + (float)applied * 3.46573590f;   // + applied*5*ln2
        wsSc[gw] = sc;
    }
}

// ---------------- Phase 2: serial combine (register-resident, 1 wave/seq) ----------------
// Lane (j, h=lane>>5) accumulates cols 16h..16h+15 of output row j; the two
// halves are summed with one shfl_xor(32). All 16 dwordx4 matrix loads are
// issued before any use -> full memory pipelining (no LDS round-trip).
__global__ __launch_bounds__(64) void crf_combine(
    const float*    __restrict__ y_pred,
    const unsigned* __restrict__ wsMT,
    const float*    __restrict__ wsS,
    const float*    __restrict__ wsSc,
    float*          __restrict__ out)
{
    const int lane = threadIdx.x;
    const int h    = lane >> 5;
    const int j    = lane & 31;
    const int seq  = blockIdx.x;

    // chunk cc, row j, dwords j*16 + 8h .. +8h+7  (cols 16h..16h+15)
    const uint4* mb = (const uint4*)(wsMT + (size_t)seq * NCH * 512);
    uint4 mA[NCH], mB[NCH];
#pragma unroll
    for (int cc = 0; cc < NCH; ++cc) {
        mA[cc] = mb[cc * 128 + j * 4 + 2 * h];
        mB[cc] = mb[cc * 128 + j * 4 + 2 * h + 1];
    }

    const float* yp = y_pred + (size_t)seq * Tt * K32;
    const float a0 = yp[j];                    // mirrored in both halves
    const float m0 = __shfl(a0, 0, 64);
    float p = __expf(a0 - m0);                 // p[j], mirrored
    float S = m0;

    float scs = 0.0f;
#pragma unroll
    for (int cc = 0; cc < NCH; ++cc) {
        S   += wsS[seq * NCH + cc];
        scs += wsSc[seq * NCH + cc];
    }

    const int cb = h << 4;                     // column base for this half
#pragma unroll
    for (int cc = 0; cc < NCH; ++cc) {
        const float cn = __shfl(p, 0, 64);     // old p[0] (deferred renorm)
        const unsigned u0 = mA[cc].x, u1 = mA[cc].y, u2 = mA[cc].z, u3 = mA[cc].w;
        const unsigned u4 = mB[cc].x, u5 = mB[cc].y, u6 = mB[cc].z, u7 = mB[cc].w;
        float acc = 0.0f;
        acc = fmaf(__shfl(p, cb +  0, 64), bf2f_lo(u0), acc);
        acc = fmaf(__shfl(p, cb +  1, 64), bf2f_hi(u0), acc);
        acc = fmaf(__shfl(p, cb +  2, 64), bf2f_lo(u1), acc);
        acc = fmaf(__shfl(p, cb +  3, 64), bf2f_hi(u1), acc);
        acc = fmaf(__shfl(p, cb +  4, 64), bf2f_lo(u2), acc);
        acc = fmaf(__shfl(p, cb +  5, 64), bf2f_hi(u2), acc);
        acc = fmaf(__shfl(p, cb +  6, 64), bf2f_lo(u3), acc);
        acc = fmaf(__shfl(p, cb +  7, 64), bf2f_hi(u3), acc);
        acc = fmaf(__shfl(p, cb +  8, 64), bf2f_lo(u4), acc);
        acc = fmaf(__shfl(p, cb +  9, 64), bf2f_hi(u4), acc);
        acc = fmaf(__shfl(p, cb + 10, 64), bf2f_lo(u5), acc);
        acc = fmaf(__shfl(p, cb + 11, 64), bf2f_hi(u5), acc);
        acc = fmaf(__shfl(p, cb + 12, 64), bf2f_lo(u6), acc);
        acc = fmaf(__shfl(p, cb + 13, 64), bf2f_hi(u6), acc);
        acc = fmaf(__shfl(p, cb + 14, 64), bf2f_lo(u7), acc);
        acc = fmaf(__shfl(p, cb + 15, 64), bf2f_hi(u7), acc);
        acc += __shfl_xor(acc, 32, 64);        // combine halves -> full dot, mirrored
        p = acc * (1.0f / cn);
        S += __logf(cn);
    }

    float sp = p;
    sp += __shfl_xor(sp,  1, 64);
    sp += __shfl_xor(sp,  2, 64);
    sp += __shfl_xor(sp,  4, 64);
    sp += __shfl_xor(sp,  8, 64);
    sp += __shfl_xor(sp, 16, 64);

    if (lane == 0) {
        out[seq] = S + __logf(sp) - scs;
    }
}

extern "C" void kernel_launch(void* const* d_in, const int* in_sizes, int n_in,
                              void* d_out, int out_size, void* d_ws, size_t ws_size,
                              hipStream_t stream) {
    const int*   labels = (const int*)  d_in[0];
    const float* y_pred = (const float*)d_in[1];
    const float* trans  = (const float*)d_in[2];
    const float* mask   = (const float*)d_in[3];
    float* out = (float*)d_out;

    // workspace carve: M^T (16 MB) | S (32 KB) | Sc (32 KB)
    unsigned* wsMT = (unsigned*)d_ws;
    float* wsS  = (float*)((char*)d_ws + (size_t)1024 * NCH * 512 * 4);
    float* wsSc = wsS + 1024 * NCH;

    crf_chunk<<<2048, 256, 0, stream>>>(labels, y_pred, trans, mask, wsMT, wsS, wsSc);
    crf_combine<<<1024, 64, 0, stream>>>(y_pred, wsMT, wsS, wsSc, out);
}

// Round 3
// 143.033 us; speedup vs baseline: 1.2060x; 1.0738x over previous
//
#include <hip/hip_runtime.h>

// CRF loss, B=1024, T=512, K=32 — chunked associative scan, register-resident.
//
// Phase 1 (crf_chunk): per chunk (4096 waves, CHL=128): N <- D_t (E^T N):
//   * contraction index k is PERMUTED (pi: slot q*8+j <-> orig row q*4+j /
//     16+q*4+j-4). A (= E^T, constant) is packed in pi-order; under pi the
//     next step's B-fragment IS the current lane's own C fragments ->
//     NO LDS and NO cross-lane ops in the serial loop.
//   * emit exps PRECOMPUTED per 64-step segment into per-wave LDS (8 KB:
//     [64][32] f32). Step loop reads sv0/sv1 with 2x ds_read_b128
//     (16-lane broadcast, conflict-free). Replaces per-step {exp (TRANS),
//     8 ds_bpermute (DS), global load} with 2 DS reads.
//   * mask ballot per segment; all-ones segments take a BRANCH-FREE loop
//     (no per-step SALU test, no BB fragmentation -> cross-step scheduling).
//   * step = 4x mfma_16x16x32_bf16 + 2 ds_read_b128 + 16 scale muls + 8 packs
//   * renorm every 8 applied steps by element (0,0) via readfirstlane
//   * CHL=128 (NCH=4): chunk issue-work is NCH-independent, but combine's
//     serial chain and wsMT traffic HALVE. 1024 WGs = 4 resident/CU exactly.
//   * one LDS transpose at kernel end (aliases the exp buffer).
// Phase 2 (crf_combine): one wave per sequence, 4 chunk matrices loaded to
//   registers up-front, lane-pair split matvecs, no LDS.

#define K32 32
#define Tt  512
#define NCH 4
#define CHL 128
#define NSEG 2

typedef float  float4v __attribute__((ext_vector_type(4)));
typedef short  short8v __attribute__((ext_vector_type(8)));

__device__ inline float bf2f_lo(unsigned d) { return __uint_as_float(d << 16); }
__device__ inline float bf2f_hi(unsigned d) { return __uint_as_float(d & 0xFFFF0000u); }

// pack two f32 -> bf16x2 dword by truncation: low16 = hi16(lo), high16 = hi16(hi)
__device__ inline unsigned pack_trunc(float hi, float lo) {
    return __builtin_amdgcn_perm(__float_as_uint(hi), __float_as_uint(lo), 0x07060302u);
}
// round-to-nearest-even bf16 (one-time constants only)
__device__ inline unsigned short f2bf_rne(float x) {
    unsigned u = __float_as_uint(x);
    return (unsigned short)((u + 0x7FFFu + ((u >> 16) & 1u)) >> 16);
}

union F8 { unsigned u[4]; short8v v; };

// ---------------- Phase 1: per-chunk matrix product (register-resident) ----------------
__global__ __launch_bounds__(256, 4) void crf_chunk(
    const int*   __restrict__ labels,
    const float* __restrict__ y_pred,
    const float* __restrict__ trans,
    const float* __restrict__ mask,
    unsigned*    __restrict__ wsMT,   // [4096][512] dwords: M^T row-major bf16x2
    float*       __restrict__ wsS,    // [4096] log-scale per chunk
    float*       __restrict__ wsSc)   // [4096] path-score per chunk
{
    __shared__ float expAll[4][64 * 32];      // 8 KB per wave: exp(emit) for one segment

    const int lane = threadIdx.x & 63;
    const int wv   = __builtin_amdgcn_readfirstlane(threadIdx.x >> 6);  // wave-uniform
    const int gw   = blockIdx.x * 4 + wv;     // global wave id (scalar)
    const int n    = lane & 15;
    const int q    = lane >> 4;
    const int seq  = gw >> 2;                 // scalar
    const int c    = gw & 3;                  // scalar

    float* eb = &expAll[wv][0];

    const float* yp  = y_pred + (size_t)seq * Tt * K32;
    const int*   lb  = labels + (size_t)seq * Tt;
    const float* mkp = mask   + (size_t)seq * Tt;
    const int tbase = c * CHL;                // scalar

    // ---- prefetch segment-0 emits (8x float4/lane, perfectly coalesced) ----
    float4 pre[8];
    {
        const float4* gs = (const float4*)(yp + (size_t)tbase * K32);
#pragma unroll
        for (int jj = 0; jj < 8; ++jj) pre[jj] = gs[jj * 64 + lane];
    }

    // ---- chunk path score + per-segment mask ballots (upfront) ----
    unsigned long long mb[NSEG];
    float sc = 0.0f;
#pragma unroll
    for (int s = 0; s < NSEG; ++s) {
        const int t = tbase + s * 64 + lane;
        const int lab0 = lb[t];
        const float mlane = mkp[t];
        float scl = yp[t * K32 + lab0] * mlane;
        if (t < Tt - 1) {
            scl += trans[lab0 * K32 + lb[t + 1]] * (mlane * mkp[t + 1]);
        }
        sc += scl;
        mb[s] = __ballot(mlane != 0.0f);
    }
    if (c == 0) mb[0] &= ~1ull;               // skip t=0 (alpha0 seeds combine)
#pragma unroll
    for (int s = 1; s < 64; s <<= 1) sc += __shfl_xor(sc, s, 64);

    // ---- constant A in pi-k-order: slot q*8+j <-> orig k = q*4+j | 16+q*4+(j-2) ----
    F8 AE0, AE1;
#pragma unroll
    for (int h = 0; h < 4; ++h) {
        const int k0 = (h < 2) ? (q * 4 + 2 * h) : (16 + q * 4 + 2 * (h - 2));
        const int k1 = k0 + 1;
        AE0.u[h] = ((unsigned)f2bf_rne(__expf(trans[k0 * K32 + n]) * 0.03125f)) |
                   (((unsigned)f2bf_rne(__expf(trans[k1 * K32 + n]) * 0.03125f)) << 16);
        AE1.u[h] = ((unsigned)f2bf_rne(__expf(trans[k0 * K32 + 16 + n]) * 0.03125f)) |
                   (((unsigned)f2bf_rne(__expf(trans[k1 * K32 + 16 + n]) * 0.03125f)) << 16);
    }

    // ---- B = identity fragments (pi-order) ----
    F8 B0, B1;
#pragma unroll
    for (int h = 0; h < 4; ++h) {
        const int r0 = (h < 2) ? (q * 4 + 2 * h) : (16 + q * 4 + 2 * (h - 2));
        const int r1 = r0 + 1;
        unsigned w0 = 0, w1 = 0;
        if (r0 == n)      w0 |= 0x3F80u;
        if (r1 == n)      w0 |= 0x3F800000u;
        if (r0 == 16 + n) w1 |= 0x3F80u;
        if (r1 == 16 + n) w1 |= 0x3F800000u;
        B0.u[h] = w0;
        B1.u[h] = w1;
    }

    float Slog    = 0.0f;
    int   applied = 0;

    const int svoff0 = q * 4;                 // lane-const LDS float offsets
    const int svoff1 = 16 + q * 4;

    auto body = [&](int i) {                  // one scan step, segment-local index i
        const float4v sv0 = *(const float4v*)&eb[i * 32 + svoff0];
        const float4v sv1 = *(const float4v*)&eb[i * 32 + svoff1];

        float4v c00 = {0.f, 0.f, 0.f, 0.f}, c01 = {0.f, 0.f, 0.f, 0.f};
        float4v c10 = {0.f, 0.f, 0.f, 0.f}, c11 = {0.f, 0.f, 0.f, 0.f};
        c00 = __builtin_amdgcn_mfma_f32_16x16x32_bf16(AE0.v, B0.v, c00, 0, 0, 0);
        c01 = __builtin_amdgcn_mfma_f32_16x16x32_bf16(AE0.v, B1.v, c01, 0, 0, 0);
        c10 = __builtin_amdgcn_mfma_f32_16x16x32_bf16(AE1.v, B0.v, c10, 0, 0, 0);
        c11 = __builtin_amdgcn_mfma_f32_16x16x32_bf16(AE1.v, B1.v, c11, 0, 0, 0);

        // D_t row-scale
        c00 *= sv0; c01 *= sv0; c10 *= sv1; c11 *= sv1;

        if ((applied & 7) == 7) {             // element-(0,0) renorm (wave-uniform)
            const float cn = __uint_as_float(
                __builtin_amdgcn_readfirstlane(__float_as_uint(c00[0])));
            const float rs = 1.0f / cn;
            c00 *= rs; c01 *= rs; c10 *= rs; c11 *= rs;
            Slog += __logf(cn);
        }
        ++applied;

        // pack C -> next B (pi-order makes this the lane's own data)
        B0.u[0] = pack_trunc(c00[1], c00[0]);
        B0.u[1] = pack_trunc(c00[3], c00[2]);
        B0.u[2] = pack_trunc(c10[1], c10[0]);
        B0.u[3] = pack_trunc(c10[3], c10[2]);
        B1.u[0] = pack_trunc(c01[1], c01[0]);
        B1.u[1] = pack_trunc(c01[3], c01[2]);
        B1.u[2] = pack_trunc(c11[1], c11[0]);
        B1.u[3] = pack_trunc(c11[3], c11[2]);
    };

    for (int seg = 0; seg < NSEG; ++seg) {
        // ---- exp + stage to LDS (contiguous ds_write_b128, per-wave private) ----
#pragma unroll
        for (int jj = 0; jj < 8; ++jj) {
            float4v e;
            e[0] = __expf(pre[jj].x); e[1] = __expf(pre[jj].y);
            e[2] = __expf(pre[jj].z); e[3] = __expf(pre[jj].w);
            *(float4v*)&eb[(jj * 64 + lane) * 4] = e;
        }
        // ---- prefetch next segment early (latency hides under step loop) ----
        if (seg + 1 < NSEG) {
            const float4* gs = (const float4*)(yp + (size_t)(tbase + (seg + 1) * 64) * K32);
#pragma unroll
            for (int jj = 0; jj < 8; ++jj) pre[jj] = gs[jj * 64 + lane];
        }

        const unsigned long long mbits = mb[seg];
        if (mbits == ~0ull) {
            // branch-free fast path (common case: mask all-ones)
#pragma unroll 8
            for (int i = 0; i < 64; ++i) body(i);
        } else {
#pragma unroll 4
            for (int i = 0; i < 64; ++i) {
                if ((mbits >> i) & 1ull) body(i);
            }
        }
    }

    // ---- one-time LDS transpose (aliases exp buffer): B frags -> M^T dump ----
    {
        unsigned* Nd = (unsigned*)eb;             // dword view, col stride 20
        *(uint2*)&Nd[n * 20 + q * 2]            = make_uint2(B0.u[0], B0.u[1]);
        *(uint2*)&Nd[n * 20 + 8 + q * 2]        = make_uint2(B0.u[2], B0.u[3]);
        *(uint2*)&Nd[(16 + n) * 20 + q * 2]     = make_uint2(B1.u[0], B1.u[1]);
        *(uint2*)&Nd[(16 + n) * 20 + 8 + q * 2] = make_uint2(B1.u[2], B1.u[3]);
    }
    const unsigned short* Ncm = (const unsigned short*)eb;
    unsigned* md = wsMT + (size_t)gw * 512;
    for (int idx = lane; idx < 512; idx += 64) {
        const int k = idx >> 4, d = idx & 15;
        const unsigned lo = Ncm[(2 * d) * 40 + k];
        const unsigned hi = Ncm[(2 * d + 1) * 40 + k];
        md[idx] = lo | (hi << 16);
    }
    if (lane == 0) {
        wsS[gw]  = Slog + (float)applied * 3.46573590f;   // + applied*5*ln2
        wsSc[gw] = sc;
    }
}

// ---------------- Phase 2: serial combine (register-resident, 1 wave/seq) ----------------
// Lane (j, h=lane>>5) accumulates cols 16h..16h+15 of output row j; the two
// halves are summed with one shfl_xor(32). All 8 dwordx4 matrix loads are
// issued before any use -> full memory pipelining (no LDS round-trip).
__global__ __launch_bounds__(64) void crf_combine(
    const float*    __restrict__ y_pred,
    const unsigned* __restrict__ wsMT,
    const float*    __restrict__ wsS,
    const float*    __restrict__ wsSc,
    float*          __restrict__ out)
{
    const int lane = threadIdx.x;
    const int h    = lane >> 5;
    const int j    = lane & 31;
    const int seq  = blockIdx.x;

    // chunk cc, row j, dwords j*16 + 8h .. +8h+7  (cols 16h..16h+15)
    const uint4* mb = (const uint4*)(wsMT + (size_t)seq * NCH * 512);
    uint4 mA[NCH], mB[NCH];
#pragma unroll
    for (int cc = 0; cc < NCH; ++cc) {
        mA[cc] = mb[cc * 128 + j * 4 + 2 * h];
        mB[cc] = mb[cc * 128 + j * 4 + 2 * h + 1];
    }

    const float* yp = y_pred + (size_t)seq * Tt * K32;
    const float a0 = yp[j];                    // mirrored in both halves
    const float m0 = __shfl(a0, 0, 64);
    float p = __expf(a0 - m0);                 // p[j], mirrored
    float S = m0;

    float scs = 0.0f;
#pragma unroll
    for (int cc = 0; cc < NCH; ++cc) {
        S   += wsS[seq * NCH + cc];
        scs += wsSc[seq * NCH + cc];
    }

    const int cb = h << 4;                     // column base for this half
#pragma unroll
    for (int cc = 0; cc < NCH; ++cc) {
        const float cn = __shfl(p, 0, 64);     // old p[0] (deferred renorm)
        const unsigned u0 = mA[cc].x, u1 = mA[cc].y, u2 = mA[cc].z, u3 = mA[cc].w;
        const unsigned u4 = mB[cc].x, u5 = mB[cc].y, u6 = mB[cc].z, u7 = mB[cc].w;
        float acc = 0.0f;
        acc = fmaf(__shfl(p, cb +  0, 64), bf2f_lo(u0), acc);
        acc = fmaf(__shfl(p, cb +  1, 64), bf2f_hi(u0), acc);
        acc = fmaf(__shfl(p, cb +  2, 64), bf2f_lo(u1), acc);
        acc = fmaf(__shfl(p, cb +  3, 64), bf2f_hi(u1), acc);
        acc = fmaf(__shfl(p, cb +  4, 64), bf2f_lo(u2), acc);
        acc = fmaf(__shfl(p, cb +  5, 64), bf2f_hi(u2), acc);
        acc = fmaf(__shfl(p, cb +  6, 64), bf2f_lo(u3), acc);
        acc = fmaf(__shfl(p, cb +  7, 64), bf2f_hi(u3), acc);
        acc = fmaf(__shfl(p, cb +  8, 64), bf2f_lo(u4), acc);
        acc = fmaf(__shfl(p, cb +  9, 64), bf2f_hi(u4), acc);
        acc = fmaf(__shfl(p, cb + 10, 64), bf2f_lo(u5), acc);
        acc = fmaf(__shfl(p, cb + 11, 64), bf2f_hi(u5), acc);
        acc = fmaf(__shfl(p, cb + 12, 64), bf2f_lo(u6), acc);
        acc = fmaf(__shfl(p, cb + 13, 64), bf2f_hi(u6), acc);
        acc = fmaf(__shfl(p, cb + 14, 64), bf2f_lo(u7), acc);
        acc = fmaf(__shfl(p, cb + 15, 64), bf2f_hi(u7), acc);
        acc += __shfl_xor(acc, 32, 64);        // combine halves -> full dot, mirrored
        p = acc * (1.0f / cn);
        S += __logf(cn);
    }

    float sp = p;
    sp += __shfl_xor(sp,  1, 64);
    sp += __shfl_xor(sp,  2, 64);
    sp += __shfl_xor(sp,  4, 64);
    sp += __shfl_xor(sp,  8, 64);
    sp += __shfl_xor(sp, 16, 64);

    if (lane == 0) {
        out[seq] = S + __logf(sp) - scs;
    }
}

extern "C" void kernel_launch(void* const* d_in, const int* in_sizes, int n_in,
                              void* d_out, int out_size, void* d_ws, size_t ws_size,
                              hipStream_t stream) {
    const int*   labels = (const int*)  d_in[0];
    const float* y_pred = (const float*)d_in[1];
    const float* trans  = (const float*)d_in[2];
    const float* mask   = (const float*)d_in[3];
    float* out = (float*)d_out;

    // workspace carve: M^T (8 MB) | S (16 KB) | Sc (16 KB)
    unsigned* wsMT = (unsigned*)d_ws;
    float* wsS  = (float*)((char*)d_ws + (size_t)1024 * NCH * 512 * 4);
    float* wsSc = wsS + 1024 * NCH;

    crf_chunk<<<1024, 256, 0, stream>>>(labels, y_pred, trans, mask, wsMT, wsS, wsSc);
    crf_combine<<<1024, 64, 0, stream>>>(y_pred, wsMT, wsS, wsSc, out);
}

// Round 4
// 141.500 us; speedup vs baseline: 1.2190x; 1.0108x over previous
//
#include <hip/hip_runtime.h>

// CRF loss, B=1024, T=512, K=32 — chunked associative scan, FULLY FUSED.
//
// One kernel, one WG (256 thr = 4 waves) per sequence. Wave wv owns chunk
// c=wv (CHL=128 steps): N <- D_t (E^T N), register-resident:
//   * contraction index k is PERMUTED (pi: slot q*8+j <-> orig row q*4+j /
//     16+q*4+j-4). A (= E^T, constant) is packed in pi-order; under pi the
//     next step's B-fragment IS the current lane's own C fragments ->
//     NO LDS and NO cross-lane ops in the serial loop.
//   * emit exps PRECOMPUTED per 64-step segment into per-wave LDS (8 KB:
//     [64][32] f32). Step loop reads sv0/sv1 with 2x ds_read_b128.
//   * mask ballot per segment; all-ones segments take a BRANCH-FREE loop.
//   * step = 4x mfma_16x16x32_bf16 + 2 ds_read_b128 + 16 scale muls + 8 packs
//   * renorm every 8 applied steps by element (0,0) via readfirstlane
// Then each wave dumps M^T + (Slog, pathscore) into its own DEAD exp buffer
// (LDS aliasing — total LDS stays 32 KB -> 4 WGs/CU, one generation),
// __syncthreads, and wave 0 runs the serial combine (4 matvecs, shfl-based)
// and writes out[seq]. This removes the second kernel launch, the 8 MB
// workspace HBM round-trip, and the inter-kernel full-device dependency —
// which benching showed was a ~78 µs fixed cost insensitive to combine's
// actual work (two rewrites + chain-halving moved it ~0).
//
// Per-wave LDS map (2048 dwords), all within expAll[wv]:
//   during scan : dwords 0..2047 = exp(emit) for current 64-step segment
//   after scan  : dwords 1024..1663 = transpose scratch (col-major, stride 20)
//                 dwords    0..511  = M^T row-major bf16x2 (row*16 + dword)
//                 dword  1984/1985  = Slog / path-score

#define K32 32
#define Tt  512
#define NCH 4
#define CHL 128
#define NSEG 2

typedef float  float4v __attribute__((ext_vector_type(4)));
typedef short  short8v __attribute__((ext_vector_type(8)));

__device__ inline float bf2f_lo(unsigned d) { return __uint_as_float(d << 16); }
__device__ inline float bf2f_hi(unsigned d) { return __uint_as_float(d & 0xFFFF0000u); }

// pack two f32 -> bf16x2 dword by truncation: low16 = hi16(lo), high16 = hi16(hi)
__device__ inline unsigned pack_trunc(float hi, float lo) {
    return __builtin_amdgcn_perm(__float_as_uint(hi), __float_as_uint(lo), 0x07060302u);
}
// round-to-nearest-even bf16 (one-time constants only)
__device__ inline unsigned short f2bf_rne(float x) {
    unsigned u = __float_as_uint(x);
    return (unsigned short)((u + 0x7FFFu + ((u >> 16) & 1u)) >> 16);
}

union F8 { unsigned u[4]; short8v v; };

__global__ __launch_bounds__(256, 4) void crf_fused(
    const int*   __restrict__ labels,
    const float* __restrict__ y_pred,
    const float* __restrict__ trans,
    const float* __restrict__ mask,
    float*       __restrict__ out)
{
    __shared__ float expAll[4][2048];         // 32 KB total

    const int lane = threadIdx.x & 63;
    const int wv   = __builtin_amdgcn_readfirstlane(threadIdx.x >> 6);  // wave-uniform
    const int n    = lane & 15;
    const int q    = lane >> 4;
    const int seq  = blockIdx.x;              // scalar
    const int c    = wv;                      // chunk id == wave id

    float* eb = &expAll[wv][0];

    const float* yp  = y_pred + (size_t)seq * Tt * K32;
    const int*   lb  = labels + (size_t)seq * Tt;
    const float* mkp = mask   + (size_t)seq * Tt;
    const int tbase = c * CHL;                // scalar

    // ---- prefetch segment-0 emits (8x float4/lane, perfectly coalesced) ----
    float4 pre[8];
    {
        const float4* gs = (const float4*)(yp + (size_t)tbase * K32);
#pragma unroll
        for (int jj = 0; jj < 8; ++jj) pre[jj] = gs[jj * 64 + lane];
    }

    // ---- chunk path score + per-segment mask ballots (upfront) ----
    unsigned long long mb[NSEG];
    float sc = 0.0f;
#pragma unroll
    for (int s = 0; s < NSEG; ++s) {
        const int t = tbase + s * 64 + lane;
        const int lab0 = lb[t];
        const float mlane = mkp[t];
        float scl = yp[t * K32 + lab0] * mlane;
        if (t < Tt - 1) {
            scl += trans[lab0 * K32 + lb[t + 1]] * (mlane * mkp[t + 1]);
        }
        sc += scl;
        mb[s] = __ballot(mlane != 0.0f);
    }
    if (c == 0) mb[0] &= ~1ull;               // skip t=0 (alpha0 seeds combine)
#pragma unroll
    for (int s = 1; s < 64; s <<= 1) sc += __shfl_xor(sc, s, 64);

    // ---- constant A in pi-k-order: slot q*8+j <-> orig k = q*4+j | 16+q*4+(j-2) ----
    F8 AE0, AE1;
#pragma unroll
    for (int h = 0; h < 4; ++h) {
        const int k0 = (h < 2) ? (q * 4 + 2 * h) : (16 + q * 4 + 2 * (h - 2));
        const int k1 = k0 + 1;
        AE0.u[h] = ((unsigned)f2bf_rne(__expf(trans[k0 * K32 + n]) * 0.03125f)) |
                   (((unsigned)f2bf_rne(__expf(trans[k1 * K32 + n]) * 0.03125f)) << 16);
        AE1.u[h] = ((unsigned)f2bf_rne(__expf(trans[k0 * K32 + 16 + n]) * 0.03125f)) |
                   (((unsigned)f2bf_rne(__expf(trans[k1 * K32 + 16 + n]) * 0.03125f)) << 16);
    }

    // ---- B = identity fragments (pi-order) ----
    F8 B0, B1;
#pragma unroll
    for (int h = 0; h < 4; ++h) {
        const int r0 = (h < 2) ? (q * 4 + 2 * h) : (16 + q * 4 + 2 * (h - 2));
        const int r1 = r0 + 1;
        unsigned w0 = 0, w1 = 0;
        if (r0 == n)      w0 |= 0x3F80u;
        if (r1 == n)      w0 |= 0x3F800000u;
        if (r0 == 16 + n) w1 |= 0x3F80u;
        if (r1 == 16 + n) w1 |= 0x3F800000u;
        B0.u[h] = w0;
        B1.u[h] = w1;
    }

    float Slog    = 0.0f;
    int   applied = 0;

    const int svoff0 = q * 4;                 // lane-const LDS float offsets
    const int svoff1 = 16 + q * 4;

    auto body = [&](int i) {                  // one scan step, segment-local index i
        const float4v sv0 = *(const float4v*)&eb[i * 32 + svoff0];
        const float4v sv1 = *(const float4v*)&eb[i * 32 + svoff1];

        float4v c00 = {0.f, 0.f, 0.f, 0.f}, c01 = {0.f, 0.f, 0.f, 0.f};
        float4v c10 = {0.f, 0.f, 0.f, 0.f}, c11 = {0.f, 0.f, 0.f, 0.f};
        c00 = __builtin_amdgcn_mfma_f32_16x16x32_bf16(AE0.v, B0.v, c00, 0, 0, 0);
        c01 = __builtin_amdgcn_mfma_f32_16x16x32_bf16(AE0.v, B1.v, c01, 0, 0, 0);
        c10 = __builtin_amdgcn_mfma_f32_16x16x32_bf16(AE1.v, B0.v, c10, 0, 0, 0);
        c11 = __builtin_amdgcn_mfma_f32_16x16x32_bf16(AE1.v, B1.v, c11, 0, 0, 0);

        // D_t row-scale
        c00 *= sv0; c01 *= sv0; c10 *= sv1; c11 *= sv1;

        if ((applied & 7) == 7) {             // element-(0,0) renorm (wave-uniform)
            const float cn = __uint_as_float(
                __builtin_amdgcn_readfirstlane(__float_as_uint(c00[0])));
            const float rs = 1.0f / cn;
            c00 *= rs; c01 *= rs; c10 *= rs; c11 *= rs;
            Slog += __logf(cn);
        }
        ++applied;

        // pack C -> next B (pi-order makes this the lane's own data)
        B0.u[0] = pack_trunc(c00[1], c00[0]);
        B0.u[1] = pack_trunc(c00[3], c00[2]);
        B0.u[2] = pack_trunc(c10[1], c10[0]);
        B0.u[3] = pack_trunc(c10[3], c10[2]);
        B1.u[0] = pack_trunc(c01[1], c01[0]);
        B1.u[1] = pack_trunc(c01[3], c01[2]);
        B1.u[2] = pack_trunc(c11[1], c11[0]);
        B1.u[3] = pack_trunc(c11[3], c11[2]);
    };

    for (int seg = 0; seg < NSEG; ++seg) {
        // ---- exp + stage to LDS (contiguous ds_write_b128, per-wave private) ----
#pragma unroll
        for (int jj = 0; jj < 8; ++jj) {
            float4v e;
            e[0] = __expf(pre[jj].x); e[1] = __expf(pre[jj].y);
            e[2] = __expf(pre[jj].z); e[3] = __expf(pre[jj].w);
            *(float4v*)&eb[(jj * 64 + lane) * 4] = e;
        }
        // ---- prefetch next segment early (latency hides under step loop) ----
        if (seg + 1 < NSEG) {
            const float4* gs = (const float4*)(yp + (size_t)(tbase + (seg + 1) * 64) * K32);
#pragma unroll
            for (int jj = 0; jj < 8; ++jj) pre[jj] = gs[jj * 64 + lane];
        }

        const unsigned long long mbits = mb[seg];
        if (mbits == ~0ull) {
            // branch-free fast path (common case: mask all-ones)
#pragma unroll 8
            for (int i = 0; i < 64; ++i) body(i);
        } else {
#pragma unroll 4
            for (int i = 0; i < 64; ++i) {
                if ((mbits >> i) & 1ull) body(i);
            }
        }
    }

    // ---- transpose into dead exp buffer: scratch at dwords 1024.., M^T at 0.. ----
    {
        unsigned* Nd = (unsigned*)eb + 1024;      // col-major scratch, col stride 20
        *(uint2*)&Nd[n * 20 + q * 2]            = make_uint2(B0.u[0], B0.u[1]);
        *(uint2*)&Nd[n * 20 + 8 + q * 2]        = make_uint2(B0.u[2], B0.u[3]);
        *(uint2*)&Nd[(16 + n) * 20 + q * 2]     = make_uint2(B1.u[0], B1.u[1]);
        *(uint2*)&Nd[(16 + n) * 20 + 8 + q * 2] = make_uint2(B1.u[2], B1.u[3]);
    }
    {
        const unsigned short* Ncm = (const unsigned short*)((unsigned*)eb + 1024);
        unsigned* md = (unsigned*)eb;             // M^T: dword = row*16 + d
        for (int idx = lane; idx < 512; idx += 64) {
            const int k = idx >> 4, d = idx & 15;
            const unsigned lo = Ncm[(2 * d) * 40 + k];
            const unsigned hi = Ncm[(2 * d + 1) * 40 + k];
            md[idx] = lo | (hi << 16);
        }
    }
    if (lane == 0) {
        eb[1984] = Slog + (float)applied * 3.46573590f;   // + applied*5*ln2
        eb[1985] = sc;
    }

    __syncthreads();

    // ---------------- combine (wave 0 only): 4 serial matvecs + logsumexp ----------------
    if (wv == 0) {
        const int h = lane >> 5;
        const int j = lane & 31;

        // chunk cc, M^T row j, dwords j*16 + 8h .. +8h+7  (cols 16h..16h+15)
        uint4 mA[NCH], mB[NCH];
#pragma unroll
        for (int cc = 0; cc < NCH; ++cc) {
            const unsigned* mt = (const unsigned*)&expAll[cc][0];
            mA[cc] = *(const uint4*)&mt[j * 16 + 8 * h];
            mB[cc] = *(const uint4*)&mt[j * 16 + 8 * h + 4];
        }

        const float a0 = yp[j];                // mirrored in both halves
        const float m0 = __shfl(a0, 0, 64);
        float p = __expf(a0 - m0);             // p[j], mirrored
        float S = m0;

        float scs = 0.0f;
#pragma unroll
        for (int cc = 0; cc < NCH; ++cc) {
            S   += expAll[cc][1984];
            scs += expAll[cc][1985];
        }

        const int cb = h << 4;                 // column base for this half
#pragma unroll
        for (int cc = 0; cc < NCH; ++cc) {
            const float cn = __shfl(p, 0, 64); // old p[0] (deferred renorm)
            const unsigned u0 = mA[cc].x, u1 = mA[cc].y, u2 = mA[cc].z, u3 = mA[cc].w;
            const unsigned u4 = mB[cc].x, u5 = mB[cc].y, u6 = mB[cc].z, u7 = mB[cc].w;
            float acc = 0.0f;
            acc = fmaf(__shfl(p, cb +  0, 64), bf2f_lo(u0), acc);
            acc = fmaf(__shfl(p, cb +  1, 64), bf2f_hi(u0), acc);
            acc = fmaf(__shfl(p, cb +  2, 64), bf2f_lo(u1), acc);
            acc = fmaf(__shfl(p, cb +  3, 64), bf2f_hi(u1), acc);
            acc = fmaf(__shfl(p, cb +  4, 64), bf2f_lo(u2), acc);
            acc = fmaf(__shfl(p, cb +  5, 64), bf2f_hi(u2), acc);
            acc = fmaf(__shfl(p, cb +  6, 64), bf2f_lo(u3), acc);
            acc = fmaf(__shfl(p, cb +  7, 64), bf2f_hi(u3), acc);
            acc = fmaf(__shfl(p, cb +  8, 64), bf2f_lo(u4), acc);
            acc = fmaf(__shfl(p, cb +  9, 64), bf2f_hi(u4), acc);
            acc = fmaf(__shfl(p, cb + 10, 64), bf2f_lo(u5), acc);
            acc = fmaf(__shfl(p, cb + 11, 64), bf2f_hi(u5), acc);
            acc = fmaf(__shfl(p, cb + 12, 64), bf2f_lo(u6), acc);
            acc = fmaf(__shfl(p, cb + 13, 64), bf2f_hi(u6), acc);
            acc = fmaf(__shfl(p, cb + 14, 64), bf2f_lo(u7), acc);
            acc = fmaf(__shfl(p, cb + 15, 64), bf2f_hi(u7), acc);
            acc += __shfl_xor(acc, 32, 64);    // combine halves -> full dot, mirrored
            p = acc * (1.0f / cn);
            S += __logf(cn);
        }

        float sp = p;
        sp += __shfl_xor(sp,  1, 64);
        sp += __shfl_xor(sp,  2, 64);
        sp += __shfl_xor(sp,  4, 64);
        sp += __shfl_xor(sp,  8, 64);
        sp += __shfl_xor(sp, 16, 64);

        if (lane == 0) {
            out[seq] = S + __logf(sp) - scs;
        }
    }
}

extern "C" void kernel_launch(void* const* d_in, const int* in_sizes, int n_in,
                              void* d_out, int out_size, void* d_ws, size_t ws_size,
                              hipStream_t stream) {
    const int*   labels = (const int*)  d_in[0];
    const float* y_pred = (const float*)d_in[1];
    const float* trans  = (const float*)d_in[2];
    const float* mask   = (const float*)d_in[3];
    float* out = (float*)d_out;

    crf_fused<<<1024, 256, 0, stream>>>(labels, y_pred, trans, mask, out);
}

// Round 5
// 141.177 us; speedup vs baseline: 1.2218x; 1.0023x over previous
//
#include <hip/hip_runtime.h>

// CRF loss, B=1024, T=512, K=32 — chunked associative scan, FULLY FUSED.
//
// One kernel, one WG (512 thr = 8 waves) per sequence. Wave wv owns chunk
// c=wv (CHL=64 steps): N <- D_t (E^T N), register-resident:
//   * contraction index k is PERMUTED (pi: slot q*8+j <-> orig row q*4+j /
//     16+q*4+j-4). A (= E^T, constant) is packed in pi-order; under pi the
//     next step's B-fragment IS the current lane's own C fragments ->
//     NO LDS and NO cross-lane ops in the serial loop.
//   * emit exps staged per 32-step sub-stage into per-wave LDS (4 KB:
//     [32][32] f32). Step loop reads sv0/sv1 with 2x ds_read_b128
//     (16-lane broadcast, conflict-free).
//   * 8 waves/WG + 4 KB/wave LDS (32 KB/WG) -> 4 WG/CU = 32 waves/CU:
//     round-4 analysis showed the scan is LATENCY-bound (VALU 37%, Mfma 20%,
//     occ 31%) — the serial chain can't fill 4 waves/SIMD. 8 waves/SIMD
//     doubles slot filling AND halves the serial depth (64 vs 128 steps).
//   * step = 4x mfma_16x16x32_bf16 + 2 ds_read_b128 + 16 scale muls + 8 packs
//   * renorm every 8 applied steps by element (0,0) via readfirstlane
// Then each wave dumps M^T + (Slog, pathscore) into its own DEAD exp buffer
// (read-to-regs-then-write aliasing keeps it in 1024 dwords), __syncthreads,
// wave 0 runs the serial combine (8 matvecs, rolling 1-chunk reg prefetch)
// and writes out[seq]. Single dispatch (round-4: the ~76 µs total-vs-kernel
// gap is harness-fixed reset overhead, insensitive to kernel structure).
//
// Per-wave LDS map (1024 dwords = expAll[wv]):
//   during scan : dwords 0..1023 = exp(emit) for current 32-step stage
//   after scan  : dwords 0..639 = transpose scratch (col-major, stride 20)
//                 then dwords 0..511 = M^T row-major bf16x2 (row*16 + d)
//                 dwords 1016/1017 = Slog / path-score

#define K32 32
#define Tt  512
#define NCH 8
#define CHL 64
#define NST 2
#define STL 32

typedef float  float4v __attribute__((ext_vector_type(4)));
typedef short  short8v __attribute__((ext_vector_type(8)));

__device__ inline float bf2f_lo(unsigned d) { return __uint_as_float(d << 16); }
__device__ inline float bf2f_hi(unsigned d) { return __uint_as_float(d & 0xFFFF0000u); }

// pack two f32 -> bf16x2 dword by truncation: low16 = hi16(lo), high16 = hi16(hi)
__device__ inline unsigned pack_trunc(float hi, float lo) {
    return __builtin_amdgcn_perm(__float_as_uint(hi), __float_as_uint(lo), 0x07060302u);
}
// round-to-nearest-even bf16 (one-time constants only)
__device__ inline unsigned short f2bf_rne(float x) {
    unsigned u = __float_as_uint(x);
    return (unsigned short)((u + 0x7FFFu + ((u >> 16) & 1u)) >> 16);
}

union F8 { unsigned u[4]; short8v v; };

__global__ __launch_bounds__(512, 8) void crf_fused(
    const int*   __restrict__ labels,
    const float* __restrict__ y_pred,
    const float* __restrict__ trans,
    const float* __restrict__ mask,
    float*       __restrict__ out)
{
    __shared__ float expAll[8][1024];         // 32 KB total -> 4 WG/CU

    const int lane = threadIdx.x & 63;
    const int wv   = __builtin_amdgcn_readfirstlane(threadIdx.x >> 6);  // wave-uniform
    const int n    = lane & 15;
    const int q    = lane >> 4;
    const int seq  = blockIdx.x;              // scalar
    const int c    = wv;                      // chunk id == wave id

    float* eb = &expAll[wv][0];

    const float* yp  = y_pred + (size_t)seq * Tt * K32;
    const int*   lb  = labels + (size_t)seq * Tt;
    const float* mkp = mask   + (size_t)seq * Tt;
    const int tbase = c * CHL;                // scalar

    // ---- chunk path score + mask ballot (64 lanes <-> 64 timesteps) ----
    float sc;
    float mlane;
    {
        const int t = tbase + lane;
        const int lab0 = lb[t];
        mlane = mkp[t];
        sc = yp[t * K32 + lab0] * mlane;
        if (t < Tt - 1) {
            sc += trans[lab0 * K32 + lb[t + 1]] * (mlane * mkp[t + 1]);
        }
#pragma unroll
        for (int s = 1; s < 64; s <<= 1) sc += __shfl_xor(sc, s, 64);
    }
    unsigned long long mbits = __ballot(mlane != 0.0f);
    if (c == 0) mbits &= ~1ull;               // skip t=0 (alpha0 seeds combine)

    // ---- constant A in pi-k-order: slot q*8+j <-> orig k = q*4+j | 16+q*4+(j-2) ----
    F8 AE0, AE1;
#pragma unroll
    for (int h = 0; h < 4; ++h) {
        const int k0 = (h < 2) ? (q * 4 + 2 * h) : (16 + q * 4 + 2 * (h - 2));
        const int k1 = k0 + 1;
        AE0.u[h] = ((unsigned)f2bf_rne(__expf(trans[k0 * K32 + n]) * 0.03125f)) |
                   (((unsigned)f2bf_rne(__expf(trans[k1 * K32 + n]) * 0.03125f)) << 16);
        AE1.u[h] = ((unsigned)f2bf_rne(__expf(trans[k0 * K32 + 16 + n]) * 0.03125f)) |
                   (((unsigned)f2bf_rne(__expf(trans[k1 * K32 + 16 + n]) * 0.03125f)) << 16);
    }

    // ---- B = identity fragments (pi-order) ----
    F8 B0, B1;
#pragma unroll
    for (int h = 0; h < 4; ++h) {
        const int r0 = (h < 2) ? (q * 4 + 2 * h) : (16 + q * 4 + 2 * (h - 2));
        const int r1 = r0 + 1;
        unsigned w0 = 0, w1 = 0;
        if (r0 == n)      w0 |= 0x3F80u;
        if (r1 == n)      w0 |= 0x3F800000u;
        if (r0 == 16 + n) w1 |= 0x3F80u;
        if (r1 == 16 + n) w1 |= 0x3F800000u;
        B0.u[h] = w0;
        B1.u[h] = w1;
    }

    float Slog    = 0.0f;
    int   applied = 0;

    const int svoff0 = q * 4;                 // lane-const LDS float offsets
    const int svoff1 = 16 + q * 4;

    auto body = [&](int i) {                  // one scan step, stage-local index i
        const float4v sv0 = *(const float4v*)&eb[i * 32 + svoff0];
        const float4v sv1 = *(const float4v*)&eb[i * 32 + svoff1];

        float4v c00 = {0.f, 0.f, 0.f, 0.f}, c01 = {0.f, 0.f, 0.f, 0.f};
        float4v c10 = {0.f, 0.f, 0.f, 0.f}, c11 = {0.f, 0.f, 0.f, 0.f};
        c00 = __builtin_amdgcn_mfma_f32_16x16x32_bf16(AE0.v, B0.v, c00, 0, 0, 0);
        c01 = __builtin_amdgcn_mfma_f32_16x16x32_bf16(AE0.v, B1.v, c01, 0, 0, 0);
        c10 = __builtin_amdgcn_mfma_f32_16x16x32_bf16(AE1.v, B0.v, c10, 0, 0, 0);
        c11 = __builtin_amdgcn_mfma_f32_16x16x32_bf16(AE1.v, B1.v, c11, 0, 0, 0);

        // D_t row-scale
        c00 *= sv0; c01 *= sv0; c10 *= sv1; c11 *= sv1;

        if ((applied & 7) == 7) {             // element-(0,0) renorm (wave-uniform)
            const float cn = __uint_as_float(
                __builtin_amdgcn_readfirstlane(__float_as_uint(c00[0])));
            const float rs = 1.0f / cn;
            c00 *= rs; c01 *= rs; c10 *= rs; c11 *= rs;
            Slog += __logf(cn);
        }
        ++applied;

        // pack C -> next B (pi-order makes this the lane's own data)
        B0.u[0] = pack_trunc(c00[1], c00[0]);
        B0.u[1] = pack_trunc(c00[3], c00[2]);
        B0.u[2] = pack_trunc(c10[1], c10[0]);
        B0.u[3] = pack_trunc(c10[3], c10[2]);
        B1.u[0] = pack_trunc(c01[1], c01[0]);
        B1.u[1] = pack_trunc(c01[3], c01[2]);
        B1.u[2] = pack_trunc(c11[1], c11[0]);
        B1.u[3] = pack_trunc(c11[3], c11[2]);
    };

    for (int st = 0; st < NST; ++st) {
        // ---- load + exp + stage one 32-step block (per-wave private LDS) ----
        const float4* gs = (const float4*)(yp + (size_t)(tbase + st * STL) * K32);
#pragma unroll
        for (int jj = 0; jj < 4; ++jj) {
            const float4 pv = gs[jj * 64 + lane];
            float4v e;
            e[0] = __expf(pv.x); e[1] = __expf(pv.y);
            e[2] = __expf(pv.z); e[3] = __expf(pv.w);
            *(float4v*)&eb[(jj * 64 + lane) * 4] = e;
        }

        const unsigned b32 = (unsigned)(mbits >> (st * 32));
        if (b32 == 0xFFFFFFFFu) {
            // branch-free fast path (common case: mask all-ones)
#pragma unroll 8
            for (int i = 0; i < STL; ++i) body(i);
        } else {
#pragma unroll 4
            for (int i = 0; i < STL; ++i) {
                if ((b32 >> i) & 1u) body(i);
            }
        }
    }

    // ---- transpose in-place in the dead exp buffer (1024 dwords) ----
    {
        unsigned* Nd = (unsigned*)eb;             // col-major scratch, stride 20
        *(uint2*)&Nd[n * 20 + q * 2]            = make_uint2(B0.u[0], B0.u[1]);
        *(uint2*)&Nd[n * 20 + 8 + q * 2]        = make_uint2(B0.u[2], B0.u[3]);
        *(uint2*)&Nd[(16 + n) * 20 + q * 2]     = make_uint2(B1.u[0], B1.u[1]);
        *(uint2*)&Nd[(16 + n) * 20 + 8 + q * 2] = make_uint2(B1.u[2], B1.u[3]);
    }
    {
        // read all pieces to regs, then overwrite region with M^T row-major.
        // (wave-private; LDS ops in order; all reads precede all writes.)
        const unsigned short* Ncm = (const unsigned short*)eb;
        unsigned r[8];
#pragma unroll
        for (int ii = 0; ii < 8; ++ii) {
            const int idx = ii * 64 + lane;
            const int k = idx >> 4, d = idx & 15;
            r[ii] = (unsigned)Ncm[(2 * d) * 40 + k] |
                    ((unsigned)Ncm[(2 * d + 1) * 40 + k] << 16);
        }
        unsigned* md = (unsigned*)eb;             // M^T: dword = row*16 + d
#pragma unroll
        for (int ii = 0; ii < 8; ++ii) md[ii * 64 + lane] = r[ii];
    }
    if (lane == 0) {
        eb[1016] = Slog + (float)applied * 3.46573590f;   // + applied*5*ln2
        eb[1017] = sc;
    }

    __syncthreads();

    // ---------------- combine (wave 0 only): 8 serial matvecs + logsumexp ----------------
    if (wv == 0) {
        const int h = lane >> 5;
        const int j = lane & 31;

        // rolling 1-chunk register prefetch of M^T row j halves (keeps VGPR low)
        uint4 cA, cB;
        {
            const unsigned* mt = (const unsigned*)&expAll[0][0];
            cA = *(const uint4*)&mt[j * 16 + 8 * h];
            cB = *(const uint4*)&mt[j * 16 + 8 * h + 4];
        }

        const float a0 = yp[j];                // mirrored in both halves
        const float m0 = __shfl(a0, 0, 64);
        float p = __expf(a0 - m0);             // p[j], mirrored
        float S = m0;

        float scs = 0.0f;
#pragma unroll
        for (int cc = 0; cc < NCH; ++cc) {
            S   += expAll[cc][1016];
            scs += expAll[cc][1017];
        }

        const int cb = h << 4;                 // column base for this half
#pragma unroll
        for (int cc = 0; cc < NCH; ++cc) {
            uint4 nA = {0, 0, 0, 0}, nB = {0, 0, 0, 0};
            if (cc + 1 < NCH) {
                const unsigned* mt = (const unsigned*)&expAll[cc + 1][0];
                nA = *(const uint4*)&mt[j * 16 + 8 * h];
                nB = *(const uint4*)&mt[j * 16 + 8 * h + 4];
            }
            const float cn = __shfl(p, 0, 64); // old p[0] (deferred renorm)
            const unsigned u0 = cA.x, u1 = cA.y, u2 = cA.z, u3 = cA.w;
            const unsigned u4 = cB.x, u5 = cB.y, u6 = cB.z, u7 = cB.w;
            float acc = 0.0f;
            acc = fmaf(__shfl(p, cb +  0, 64), bf2f_lo(u0), acc);
            acc = fmaf(__shfl(p, cb +  1, 64), bf2f_hi(u0), acc);
            acc = fmaf(__shfl(p, cb +  2, 64), bf2f_lo(u1), acc);
            acc = fmaf(__shfl(p, cb +  3, 64), bf2f_hi(u1), acc);
            acc = fmaf(__shfl(p, cb +  4, 64), bf2f_lo(u2), acc);
            acc = fmaf(__shfl(p, cb +  5, 64), bf2f_hi(u2), acc);
            acc = fmaf(__shfl(p, cb +  6, 64), bf2f_lo(u3), acc);
            acc = fmaf(__shfl(p, cb +  7, 64), bf2f_hi(u3), acc);
            acc = fmaf(__shfl(p, cb +  8, 64), bf2f_lo(u4), acc);
            acc = fmaf(__shfl(p, cb +  9, 64), bf2f_hi(u4), acc);
            acc = fmaf(__shfl(p, cb + 10, 64), bf2f_lo(u5), acc);
            acc = fmaf(__shfl(p, cb + 11, 64), bf2f_hi(u5), acc);
            acc = fmaf(__shfl(p, cb + 12, 64), bf2f_lo(u6), acc);
            acc = fmaf(__shfl(p, cb + 13, 64), bf2f_hi(u6), acc);
            acc = fmaf(__shfl(p, cb + 14, 64), bf2f_lo(u7), acc);
            acc = fmaf(__shfl(p, cb + 15, 64), bf2f_hi(u7), acc);
            acc += __shfl_xor(acc, 32, 64);    // combine halves -> full dot, mirrored
            p = acc * (1.0f / cn);
            S += __logf(cn);
            cA = nA; cB = nB;
        }

        float sp = p;
        sp += __shfl_xor(sp,  1, 64);
        sp += __shfl_xor(sp,  2, 64);
        sp += __shfl_xor(sp,  4, 64);
        sp += __shfl_xor(sp,  8, 64);
        sp += __shfl_xor(sp, 16, 64);

        if (lane == 0) {
            out[seq] = S + __logf(sp) - scs;
        }
    }
}

extern "C" void kernel_launch(void* const* d_in, const int* in_sizes, int n_in,
                              void* d_out, int out_size, void* d_ws, size_t ws_size,
                              hipStream_t stream) {
    const int*   labels = (const int*)  d_in[0];
    const float* y_pred = (const float*)d_in[1];
    const float* trans  = (const float*)d_in[2];
    const float* mask   = (const float*)d_in[3];
    float* out = (float*)d_out;

    crf_fused<<<1024, 512, 0, stream>>>(labels, y_pred, trans, mask, out);
}